// Round 9
// baseline (281.750 us; speedup 1.0000x reference)
//
#include <hip/hip_runtime.h>
#include <math.h>

// B=8, H=8, N=4096, D=64 ; fft_size=8192, nf=4097 ; packed complex FFT M=4096
// Four-step: 4096 = 64 x 64.  m = 64*m1 + m0,  k = 64*k0 + k1.
// Round 9: occupancy push. All FFT kernels use 32-column LDS tiles (~17-18 KB)
// -> 8 blocks/CU. FFT64 = radix-8 x radix-8 in registers (2 LDS phases).
// fwd1 skips the zero upper half via template<ZUP>.

#define PI_F 3.14159265358979323846f
#define TWO_PI_F 6.283185307179586f

__device__ __forceinline__ int r8(int k) {   // swap the two base-8 digits
    return ((k & 7) << 3) | (k >> 3);
}

// ---------------------------------------------------------------------------
// Twiddle tables (global): tw4096[j]=(cos,sin)(2pi j/4096); tw8192[j] same /8192
// (j<4096); e64[j]=(cos,sin)(2pi j/64), j<64.
// ---------------------------------------------------------------------------
__global__ __launch_bounds__(512) void gen_tw_kernel(float2* __restrict__ tw4096,
                                                     float2* __restrict__ tw8192,
                                                     float2* __restrict__ e64)
{
    int idx = blockIdx.x * 512 + threadIdx.x;
    if (idx < 4096) {
        float s, c; __sincosf(TWO_PI_F * (float)idx * (1.0f / 4096.0f), &s, &c);
        tw4096[idx] = make_float2(c, s);
    } else if (idx < 8192) {
        int j = idx - 4096;
        float s, c; __sincosf(TWO_PI_F * (float)j * (1.0f / 8192.0f), &s, &c);
        tw8192[j] = make_float2(c, s);
    } else if (idx < 8256) {
        int j = idx - 8192;
        float s, c; __sincosf(TWO_PI_F * (float)j * (1.0f / 64.0f), &s, &c);
        e64[j] = make_float2(c, s);
    }
}

// ---------------------------------------------------------------------------
// 8-point FFT in registers. sgn=-1: X[k]=sum e^{-2pi i nk/8} x[n]; sgn=+1 conj.
// ---------------------------------------------------------------------------
__device__ __forceinline__ void fft8_regs(float2* v, float sgn) {
    float t0r = v[0].x + v[4].x, t0i = v[0].y + v[4].y;
    float t1r = v[0].x - v[4].x, t1i = v[0].y - v[4].y;
    float t2r = v[2].x + v[6].x, t2i = v[2].y + v[6].y;
    float t3r = v[2].x - v[6].x, t3i = v[2].y - v[6].y;
    float e0r = t0r + t2r, e0i = t0i + t2i;
    float e2r = t0r - t2r, e2i = t0i - t2i;
    float e1r = t1r - sgn * t3i, e1i = t1i + sgn * t3r;   // t1 + sgn*i*t3
    float e3r = t1r + sgn * t3i, e3i = t1i - sgn * t3r;
    float u0r = v[1].x + v[5].x, u0i = v[1].y + v[5].y;
    float u1r = v[1].x - v[5].x, u1i = v[1].y - v[5].y;
    float u2r = v[3].x + v[7].x, u2i = v[3].y + v[7].y;
    float u3r = v[3].x - v[7].x, u3i = v[3].y - v[7].y;
    float o0r = u0r + u2r, o0i = u0i + u2i;
    float o2r = u0r - u2r, o2i = u0i - u2i;
    float o1r = u1r - sgn * u3i, o1i = u1i + sgn * u3r;
    float o3r = u1r + sgn * u3i, o3i = u1i - sgn * u3r;
    const float C = 0.70710678118654752f;
    float w1r = C * (o1r - sgn * o1i), w1i = C * (o1i + sgn * o1r);
    float w2r = -sgn * o2i,            w2i = sgn * o2r;
    float w3r = -C * (o3r + sgn * o3i), w3i = C * (sgn * o3r - o3i);
    v[0] = make_float2(e0r + o0r, e0i + o0i);
    v[4] = make_float2(e0r - o0r, e0i - o0i);
    v[1] = make_float2(e1r + w1r, e1i + w1i);
    v[5] = make_float2(e1r - w1r, e1i - w1i);
    v[2] = make_float2(e2r + w2r, e2i + w2i);
    v[6] = make_float2(e2r - w2r, e2i - w2i);
    v[3] = make_float2(e3r + w3r, e3i + w3i);
    v[7] = make_float2(e3r - w3r, e3i - w3i);
}

// ---------------------------------------------------------------------------
// FFT64 over rows of zz[64][32] (float2). Each thread: one FFT8 per phase.
// DIF: natural rows in -> slot r8(k) out. DIT: slot r8(k) in -> natural out.
// col in [0,32), j in [0,8). act gates inactive cols. ZUP: rows>=32 are zero
// (phase A of DIF only reads rows 8r+j, r<4 when ZUP).
// ---------------------------------------------------------------------------
template<bool ZUP>
__device__ __forceinline__ void fft64_dif32(float2* zz, int col, int j, float sgn,
                                            bool act, const float2* e64s) {
    if (act) {
        float2 v[8];
        #pragma unroll
        for (int r = 0; r < 8; ++r) {
            if (ZUP && r >= 4) v[r] = make_float2(0.0f, 0.0f);
            else v[r] = zz[(8 * r + j) * 32 + col];
        }
        fft8_regs(v, sgn);
        #pragma unroll
        for (int r = 1; r < 8; ++r) {
            float2 t = e64s[j * r];
            float c = t.x, s = sgn * t.y;
            float vr = v[r].x, vi = v[r].y;
            v[r] = make_float2(vr * c - vi * s, vr * s + vi * c);
        }
        #pragma unroll
        for (int r = 0; r < 8; ++r) zz[(8 * r + j) * 32 + col] = v[r];
    }
    __syncthreads();
    if (act) {
        float2 v[8];
        #pragma unroll
        for (int r = 0; r < 8; ++r) v[r] = zz[(8 * j + r) * 32 + col];
        fft8_regs(v, sgn);
        #pragma unroll
        for (int r = 0; r < 8; ++r) zz[(8 * j + r) * 32 + col] = v[r];
    }
    __syncthreads();
}

__device__ __forceinline__ void fft64_dit32(float2* zz, int col, int j, float sgn,
                                            bool act, const float2* e64s) {
    if (act) {
        float2 v[8];
        #pragma unroll
        for (int r = 0; r < 8; ++r) v[r] = zz[(8 * j + r) * 32 + col];
        fft8_regs(v, sgn);
        #pragma unroll
        for (int r = 1; r < 8; ++r) {
            float2 t = e64s[j * r];
            float c = t.x, s = sgn * t.y;
            float vr = v[r].x, vi = v[r].y;
            v[r] = make_float2(vr * c - vi * s, vr * s + vi * c);
        }
        #pragma unroll
        for (int r = 0; r < 8; ++r) zz[(8 * j + r) * 32 + col] = v[r];
    }
    __syncthreads();
    if (act) {
        float2 v[8];
        #pragma unroll
        for (int r = 0; r < 8; ++r) v[r] = zz[(8 * r + j) * 32 + col];
        fft8_regs(v, sgn);
        #pragma unroll
        for (int r = 0; r < 8; ++r) zz[(8 * r + j) * 32 + col] = v[r];
    }
    __syncthreads();
}

// ---------------------------------------------------------------------------
// MLP stage 1: hidden activations r[k][64].
// ---------------------------------------------------------------------------
__global__ __launch_bounds__(256) void mlp_hidden_kernel(
    const float* __restrict__ w_in, const float* __restrict__ b_in,
    const float* __restrict__ w_layers, const float* __restrict__ b_layers,
    float* __restrict__ rbuf)
{
    const int lane = threadIdx.x & 63;
    const int k = blockIdx.x * 4 + (threadIdx.x >> 6);
    if (k > 4096) return;
    const float pos = PI_F * (float)k * (1.0f / 4096.0f);
    float xv = fmaf(pos, w_in[lane], b_in[lane]);
    for (int l = 0; l < 3; ++l) {
        float ss = xv * xv;
        #pragma unroll
        for (int o = 1; o < 64; o <<= 1) ss += __shfl_xor(ss, o, 64);
        float r = xv / (sqrtf(ss * (1.0f / 64.0f)) + 1e-8f);
        r = fmaxf(r, 0.0f);
        const float* W = w_layers + l * 4096;
        float a0 = 0.f, a1 = 0.f, a2 = 0.f, a3 = 0.f;
        for (int i = 0; i < 64; i += 4) {
            a0 = fmaf(__shfl(r, i, 64),     W[(i) * 64 + lane],     a0);
            a1 = fmaf(__shfl(r, i + 1, 64), W[(i + 1) * 64 + lane], a1);
            a2 = fmaf(__shfl(r, i + 2, 64), W[(i + 2) * 64 + lane], a2);
            a3 = fmaf(__shfl(r, i + 3, 64), W[(i + 3) * 64 + lane], a3);
        }
        xv = ((a0 + a1) + (a2 + a3)) + b_layers[l * 64 + lane];
    }
    float ss = xv * xv;
    #pragma unroll
    for (int o = 1; o < 64; o <<= 1) ss += __shfl_xor(ss, o, 64);
    float r = xv / (sqrtf(ss * (1.0f / 64.0f)) + 1e-8f);
    r = fmaxf(r, 0.0f);
    rbuf[(size_t)k * 64 + lane] = r;
}

// ---------------------------------------------------------------------------
// MLP stage 2: res[4097][1024] = r @ w_out + b_out.
// ---------------------------------------------------------------------------
__global__ __launch_bounds__(256) void mlp_out_kernel(
    const float* __restrict__ rbuf, const float* __restrict__ w_out,
    const float* __restrict__ b_out, float* __restrict__ res)
{
    __shared__ float rl[16 * 64];
    const int tid = threadIdx.x;
    const int nt = blockIdx.x, kt = blockIdx.y;
    for (int it = 0; it < 4; ++it) {
        int idx = it * 256 + tid;
        int row = idx >> 6, i = idx & 63;
        int k = kt * 16 + row;
        rl[idx] = (k <= 4096) ? rbuf[(size_t)k * 64 + i] : 0.0f;
    }
    __syncthreads();
    const int n = nt * 256 + tid;
    float acc[16];
    #pragma unroll
    for (int j = 0; j < 16; ++j) acc[j] = 0.0f;
    for (int i = 0; i < 64; ++i) {
        float wv = w_out[(size_t)i * 1024 + n];
        #pragma unroll
        for (int j = 0; j < 16; ++j)
            acc[j] = fmaf(rl[j * 64 + i], wv, acc[j]);
    }
    float bv = b_out[n];
    for (int j = 0; j < 16; ++j) {
        int k = kt * 16 + j;
        if (k <= 4096) res[(size_t)k * 1024 + n] = acc[j] + bv;
    }
}

// ---------------------------------------------------------------------------
// Stage A (d-half split): block=(m0, dh, lslab). FFT64 over m1 (upper zero),
// twiddle W4096^{-m0*k1}, write Y[lslab][k1][m0][d].
// ---------------------------------------------------------------------------
__global__ __launch_bounds__(256, 8) void fwd1_kernel(const float* __restrict__ x,
                                                      float2* __restrict__ Y,
                                                      const float2* __restrict__ tw4096,
                                                      const float2* __restrict__ e64g,
                                                      int slab_base)
{
    __shared__ float2 zz[64 * 32];         // [m1 64][d32 32]
    __shared__ float2 e64s[64];
    __shared__ float2 twA[64];             // twA[k1] = tw4096[m0*k1]
    const int tid = threadIdx.x;
    const int bx = blockIdx.x;             // 0..127
    const int m0 = bx >> 1, dh = bx & 1;
    const int lslab = blockIdx.y;
    if (tid < 64) e64s[tid] = e64g[tid];
    else if (tid < 128) twA[tid - 64] = tw4096[m0 * (tid - 64)];
    const float* xs = x + (size_t)(slab_base + lslab) * 262144 + 32 * dh;
    for (int it = 0; it < 4; ++it) {
        int slot = it * 256 + tid;           // m1*32 + dd, m1 < 32
        int m1 = slot >> 5, dd = slot & 31;
        float vr = xs[(size_t)(128 * m1 + 2 * m0) * 64 + dd];
        float vi = xs[(size_t)(128 * m1 + 2 * m0 + 1) * 64 + dd];
        zz[slot] = make_float2(vr, vi);      // rows >= 32 stay uninit (ZUP)
    }
    __syncthreads();
    const int col = tid & 31, j = tid >> 5;
    fft64_dif32<true>(zz, col, j, -1.0f, true, e64s);
    float2* Ys = Y + (size_t)lslab * 262144 + (size_t)m0 * 64 + 32 * dh;
    for (int og = 0; og < 8; ++og) {
        int k1 = og * 8 + j;
        float2 v = zz[r8(k1) * 32 + col];
        float2 t = twA[k1];                  // angle -2pi*m0*k1/4096
        float c = t.x, s = -t.y;
        Ys[(size_t)k1 * 4096 + col] = make_float2(v.x * c - v.y * s,
                                                  v.x * s + v.y * c);
    }
}

// ---------------------------------------------------------------------------
// Stage B (IN-PLACE on Y, d-quarter split): block=(k1-pair, dq, lslab).
// FFT64 over m0 -> C at slot r8(k0); spectral on pairs (k, 4096-k); inverse
// FFT64 (DIT) -> natural m0; twiddle W4096^{+m0*k1}; write back.
// LDS cols: plane A = [0,16), plane B = [16,32).
// ---------------------------------------------------------------------------
__global__ __launch_bounds__(256, 8) void midspec_kernel(float2* __restrict__ Y,
                                                         const float* __restrict__ res,
                                                         const float2* __restrict__ tw4096,
                                                         const float2* __restrict__ tw8192,
                                                         const float2* __restrict__ e64g,
                                                         int slab_base)
{
    __shared__ float2 zz[64 * 32];         // [row 64][col 32]
    __shared__ float2 e64s[64];
    __shared__ float2 twS[64];             // twS[k0] = tw8192[k0*64+k1a]
    __shared__ float2 twB[128];            // twB[pl*64+m0] = tw4096[m0*k1(pl)]
    const int tid = threadIdx.x;
    const int bx = blockIdx.x;             // 0..131
    const int k1p = bx >> 2, dq = bx & 3;
    const int lslab = blockIdx.y;
    const int h = (slab_base + lslab) & 7;
    const bool pairwg = (k1p >= 1 && k1p <= 31);
    const int k1a = k1p;
    const int k1b = pairwg ? (64 - k1p) : k1p;
    const int NC = pairwg ? 32 : 16;

    if (tid < 64) e64s[tid] = e64g[tid];
    else if (tid < 128) twS[tid - 64] = tw8192[(tid - 64) * 64 + k1a];
    else {
        int i = tid - 128;                 // 0..127
        int kk1 = (i < 64) ? k1a : k1b;
        twB[i] = tw4096[(i & 63) * kk1];
    }

    const float4* Pa4 = (const float4*)(Y + (size_t)lslab * 262144 + (size_t)k1a * 4096);
    for (int it = 0; it < 2; ++it) {
        int idx4 = it * 256 + tid;         // 0..511 : m0*8 + f
        int m0 = idx4 >> 3, f = idx4 & 7;
        float4 v = Pa4[m0 * 32 + 8 * dq + f];
        *(float4*)&zz[m0 * 32 + 2 * f] = v;
    }
    if (pairwg) {
        const float4* Pb4 = (const float4*)(Y + (size_t)lslab * 262144 + (size_t)k1b * 4096);
        for (int it = 0; it < 2; ++it) {
            int idx4 = it * 256 + tid;
            int m0 = idx4 >> 3, f = idx4 & 7;
            float4 v = Pb4[m0 * 32 + 8 * dq + f];
            *(float4*)&zz[m0 * 32 + 16 + 2 * f] = v;
        }
    }
    __syncthreads();
    const int col = tid & 31, j = tid >> 5;
    fft64_dif32<false>(zz, col, j, -1.0f, col < NC, e64s);

    // spectral multiply on conjugate pairs; each slot touched exactly once
    const int nit = pairwg ? 4 : 2;
    for (int it = 0; it < nit; ++it) {
        int item = it * 256 + tid;         // k0*16 + dl
        int k0 = item >> 4, dl = item & 15;
        int c = h * 128 + 16 * dq + dl;
        if (k1p == 0 && k0 == 0) {
            // DC (k=0, slot row r8(0)=0) and k=2048 (k0=32, slot row r8(32)=4)
            float2 C0 = zz[dl];
            float X0 = C0.x + C0.y, XN = C0.x - C0.y;
            float a0 = res[c], aN = res[(size_t)4096 * 1024 + c];
            float S0 = a0 * X0, SN = aN * XN;
            zz[dl] = make_float2(0.5f * (S0 + SN), 0.5f * (S0 - SN));
            int p2 = 4 * 32 + dl;
            float2 Cq = zz[p2];
            float ar = res[(size_t)2048 * 1024 + c], ai = res[(size_t)2048 * 1024 + c + 64];
            float Sr = ar * Cq.x + ai * Cq.y;
            float Si = ai * Cq.x - ar * Cq.y;
            zz[p2] = make_float2(Sr, -Si);
        } else {
            int k0p, coff;
            if (pairwg)          { k0p = 63 - k0;        coff = 16; }
            else if (k1p == 0)   { k0p = (64 - k0) & 63; coff = 0;  }
            else /* k1p == 32 */ { k0p = 63 - k0;        coff = 0;  }
            int sa = r8(k0)  * 32 + dl;
            int sb = r8(k0p) * 32 + coff + dl;
            int k  = k0 * 64 + k1a;
            int km = 4096 - k;
            float2 Ck = zz[sa], Cm = zz[sb];
            float Er = 0.5f * (Ck.x + Cm.x), Ei = 0.5f * (Ck.y - Cm.y);
            float Dr = 0.5f * (Ck.x - Cm.x), Di = 0.5f * (Ck.y + Cm.y);
            float Or = Di, Oi = -Dr;
            float2 tk = twS[k0];                 // angle -2pi*k/8192 -> conj
            float cw = tk.x, sw = -tk.y;
            float Tr = Or * cw - Oi * sw, Ti = Or * sw + Oi * cw;
            float Xkr = Er + Tr, Xki = Ei + Ti;
            float Xmr = Er - Tr, Xmi = Ti - Ei;
            float akr = res[(size_t)k * 1024 + c],  aki = res[(size_t)k * 1024 + c + 64];
            float amr = res[(size_t)km * 1024 + c], ami = res[(size_t)km * 1024 + c + 64];
            float Skr = akr * Xkr - aki * Xki, Ski = akr * Xki + aki * Xkr;
            float Smr = amr * Xmr - ami * Xmi, Smi = amr * Xmi + ami * Xmr;
            float Epr = 0.5f * (Skr + Smr), Epi = 0.5f * (Ski - Smi);
            float Ddr = 0.5f * (Skr - Smr), Ddi = 0.5f * (Ski + Smi);
            float Opr = Ddr * cw + Ddi * sw, Opi = Ddi * cw - Ddr * sw;
            zz[sa] = make_float2(Epr - Opi, Epi + Opr);
            zz[sb] = make_float2(Epr + Opi, Opr - Epi);
        }
    }
    __syncthreads();
    fft64_dit32(zz, col, j, +1.0f, col < NC, e64s);

    // write back IN-PLACE to the same Y plane quarters this block loaded
    const int nit2 = pairwg ? 8 : 4;
    for (int it = 0; it < nit2; ++it) {
        int item = it * 256 + tid;          // pl*1024 + m0*16 + dl
        int pl = item >> 10, rem = item & 1023;
        int m0 = rem >> 4, dl = rem & 15;
        int k1 = pl ? k1b : k1a;
        float2 v = zz[m0 * 32 + pl * 16 + dl];
        float2 t = twB[pl * 64 + m0];       // angle +2pi*m0*k1/4096
        float c2 = t.x, s = t.y;
        Y[(size_t)lslab * 262144 + (size_t)k1 * 4096 + (size_t)m0 * 64 + 16 * dq + dl] =
            make_float2(v.x * c2 - v.y * s, v.x * s + v.y * c2);
    }
}

// ---------------------------------------------------------------------------
// Stage C (d-half split): block=(m0, dh, lslab). Inverse FFT64 over k1
// (natural in -> r8 out); z'[64m1+m0] at slot r8(m1); write rows 2m, 2m+1.
// ---------------------------------------------------------------------------
__global__ __launch_bounds__(256, 8) void inv2_kernel(const float2* __restrict__ Y,
                                                      float* __restrict__ out,
                                                      const float2* __restrict__ e64g,
                                                      int slab_base)
{
    __shared__ float2 zz[64 * 32];         // [k1 64][d32 32]
    __shared__ float2 e64s[64];
    const int tid = threadIdx.x;
    const int bx = blockIdx.x;             // 0..127
    const int m0 = bx >> 1, dh = bx & 1;
    const int lslab = blockIdx.y;
    if (tid < 64) e64s[tid] = e64g[tid];
    const float4* Ys4 = (const float4*)(Y + (size_t)lslab * 262144 + (size_t)m0 * 64);
    for (int it = 0; it < 4; ++it) {
        int idx4 = it * 256 + tid;          // 0..1023 : k1*16 + f
        int k1 = idx4 >> 4, f = idx4 & 15;
        float4 v = Ys4[k1 * 2048 + 16 * dh + f];
        *(float4*)&zz[k1 * 32 + 2 * f] = v;
    }
    __syncthreads();
    const int col = tid & 31, j = tid >> 5;
    fft64_dif32<false>(zz, col, j, +1.0f, true, e64s);
    float* os = out + (size_t)(slab_base + lslab) * 262144 + 32 * dh;
    const float sc = 1.0f / 4096.0f;
    for (int it = 0; it < 4; ++it) {
        int slot = it * 256 + tid;          // m1*32 + dd, m1 < 32
        int m1 = slot >> 5, dd = slot & 31;
        float2 v = zz[r8(m1) * 32 + dd];
        os[(size_t)(128 * m1 + 2 * m0) * 64 + dd]     = v.x * sc;
        os[(size_t)(128 * m1 + 2 * m0 + 1) * 64 + dd] = v.y * sc;
    }
}

// ===========================================================================
// Fallback path (round-1, verified): monolithic per-column kernel
// ===========================================================================
#define PADF(i) ((i) + ((i) >> 5))

__device__ __forceinline__ unsigned dr4_12(unsigned k) {
    unsigned rb = __brev(k) >> 20;
    return ((rb & 0x555u) << 1) | ((rb >> 1) & 0x555u);
}

__global__ __launch_bounds__(64) void rpe_mlp_kernel(
    const float* __restrict__ w_in, const float* __restrict__ b_in,
    const float* __restrict__ w_layers, const float* __restrict__ b_layers,
    const float* __restrict__ w_out, const float* __restrict__ b_out,
    float* __restrict__ res)
{
    const int k = blockIdx.x;
    const int lane = threadIdx.x;
    const float pos = PI_F * (float)k * (1.0f / 4096.0f);
    float xv = fmaf(pos, w_in[lane], b_in[lane]);
    for (int l = 0; l < 3; ++l) {
        float ss = xv * xv;
        #pragma unroll
        for (int o = 1; o < 64; o <<= 1) ss += __shfl_xor(ss, o, 64);
        float rms = sqrtf(ss * (1.0f / 64.0f));
        float r = xv / (rms + 1e-8f);
        r = r > 0.0f ? r : 0.0f;
        const float* W = w_layers + l * 64 * 64;
        float acc = b_layers[l * 64 + lane];
        for (int i = 0; i < 64; ++i)
            acc = fmaf(__shfl(r, i, 64), W[i * 64 + lane], acc);
        xv = acc;
    }
    float ss = xv * xv;
    #pragma unroll
    for (int o = 1; o < 64; o <<= 1) ss += __shfl_xor(ss, o, 64);
    float rms = sqrtf(ss * (1.0f / 64.0f));
    float r = xv / (rms + 1e-8f);
    r = r > 0.0f ? r : 0.0f;
    float acc[16];
    #pragma unroll
    for (int u = 0; u < 16; ++u) acc[u] = b_out[u * 64 + lane];
    for (int i = 0; i < 64; ++i) {
        float rv = __shfl(r, i, 64);
        const float* Wrow = w_out + i * 1024;
        #pragma unroll
        for (int u = 0; u < 16; ++u)
            acc[u] = fmaf(rv, Wrow[u * 64 + lane], acc[u]);
    }
    float* dst = res + (size_t)k * 1024;
    #pragma unroll
    for (int u = 0; u < 16; ++u) dst[u * 64 + lane] = acc[u];
}

__global__ __launch_bounds__(256) void fftconv_kernel(
    const float* __restrict__ x, const float* __restrict__ res,
    float* __restrict__ out)
{
    __shared__ float re[PADF(4095) + 1];
    __shared__ float im[PADF(4095) + 1];
    const int tid = threadIdx.x;
    const int blk = blockIdx.x;
    const int d = (blk >> 3) & 63;
    const int slab = (blk & 7) | ((blk >> 9) << 3);
    const int h = slab & 7;
    const size_t base = (size_t)slab * 4096 * 64 + (size_t)d;
    const float* xc = x + base;
    float* oc = out + base;
    const int c = h * 128 + d;
    for (int m = tid; m < 2048; m += 256) {
        re[PADF(m)] = xc[(size_t)(2 * m) * 64];
        im[PADF(m)] = xc[(size_t)(2 * m + 1) * 64];
    }
    for (int m = 2048 + tid; m < 4096; m += 256) { re[PADF(m)] = 0.0f; im[PADF(m)] = 0.0f; }
    __syncthreads();
    for (int S = 1024; S >= 1; S >>= 2) {
        const float ab = -TWO_PI_F / (float)(4 * S);
        for (int j = tid; j < 1024; j += 256) {
            const int q = j & (S - 1);
            const int i0 = ((j & ~(S - 1)) << 2) | q;
            const int p0 = PADF(i0), p1 = PADF(i0 + S), p2 = PADF(i0 + 2 * S), p3 = PADF(i0 + 3 * S);
            float x0r = re[p0], x0i = im[p0], x1r = re[p1], x1i = im[p1];
            float x2r = re[p2], x2i = im[p2], x3r = re[p3], x3i = im[p3];
            float A0r = x0r + x2r, A0i = x0i + x2i, A1r = x0r - x2r, A1i = x0i - x2i;
            float A2r = x1r + x3r, A2i = x1i + x3i, A3r = x1r - x3r, A3i = x1i - x3i;
            float s1, c1; __sincosf(ab * (float)q, &s1, &c1);
            float c2 = c1 * c1 - s1 * s1, s2 = 2.0f * c1 * s1;
            float c3 = c2 * c1 - s2 * s1, s3 = s2 * c1 + c2 * s1;
            re[p0] = A0r + A2r; im[p0] = A0i + A2i;
            float t1r = A1r + A3i, t1i = A1i - A3r;
            re[p1] = t1r * c1 - t1i * s1; im[p1] = t1r * s1 + t1i * c1;
            float t2r = A0r - A2r, t2i = A0i - A2i;
            re[p2] = t2r * c2 - t2i * s2; im[p2] = t2r * s2 + t2i * c2;
            float t3r = A1r - A3i, t3i = A1i + A3r;
            re[p3] = t3r * c3 - t3i * s3; im[p3] = t3r * s3 + t3i * c3;
        }
        __syncthreads();
    }
    for (int k = tid; k <= 2048; k += 256) {
        if (k == 0) {
            float C0r = re[0], C0i = im[0];
            float X0 = C0r + C0i, XN = C0r - C0i;
            float a0 = res[c], aN = res[(size_t)4096 * 1024 + c];
            float S0 = a0 * X0, SN = aN * XN;
            re[0] = 0.5f * (S0 + SN); im[0] = 0.5f * (S0 - SN);
        } else if (k == 2048) {
            const int p = PADF(2);
            float Cr = re[p], Ci = im[p];
            float ar = res[(size_t)2048 * 1024 + c], ai = res[(size_t)2048 * 1024 + c + 64];
            float Sr = ar * Cr + ai * Ci, Si = ai * Cr - ar * Ci;
            re[p] = Sr; im[p] = -Si;
        } else {
            const int pk = PADF((int)dr4_12((unsigned)k));
            const int pm = PADF((int)dr4_12((unsigned)(4096 - k)));
            float Ckr = re[pk], Cki = im[pk];
            float Cmr = re[pm], Cmi = im[pm];
            float Er = 0.5f * (Ckr + Cmr), Ei = 0.5f * (Cki - Cmi);
            float Dr = 0.5f * (Ckr - Cmr), Di = 0.5f * (Cki + Cmi);
            float Or = Di, Oi = -Dr;
            float sw, cw; __sincosf(-TWO_PI_F * (float)k * (1.0f / 8192.0f), &sw, &cw);
            float Tr = Or * cw - Oi * sw, Ti = Or * sw + Oi * cw;
            float Xkr = Er + Tr, Xki = Ei + Ti;
            float Xmr = Er - Tr, Xmi = Ti - Ei;
            float akr = res[(size_t)k * 1024 + c], aki = res[(size_t)k * 1024 + c + 64];
            float amr = res[(size_t)(4096 - k) * 1024 + c], ami = res[(size_t)(4096 - k) * 1024 + c + 64];
            float Skr = akr * Xkr - aki * Xki, Ski = akr * Xki + aki * Xkr;
            float Smr = amr * Xmr - ami * Xmi, Smi = amr * Xmi + ami * Xmr;
            float Epr = 0.5f * (Skr + Smr), Epi = 0.5f * (Ski - Smi);
            float Ddr = 0.5f * (Skr - Smr), Ddi = 0.5f * (Ski + Smi);
            float Opr = Ddr * cw + Ddi * sw, Opi = Ddi * cw - Ddr * sw;
            re[pk] = Epr - Opi; im[pk] = Epi + Opr;
            re[pm] = Epr + Opi; im[pm] = Opr - Epi;
        }
    }
    __syncthreads();
    for (int S = 1; S <= 1024; S <<= 2) {
        const float ab = TWO_PI_F / (float)(4 * S);
        for (int j = tid; j < 1024; j += 256) {
            const int q = j & (S - 1);
            const int i0 = ((j & ~(S - 1)) << 2) | q;
            const int p0 = PADF(i0), p1 = PADF(i0 + S), p2 = PADF(i0 + 2 * S), p3 = PADF(i0 + 3 * S);
            float y0r = re[p0], y0i = im[p0], y1r = re[p1], y1i = im[p1];
            float y2r = re[p2], y2i = im[p2], y3r = re[p3], y3i = im[p3];
            float s1, c1; __sincosf(ab * (float)q, &s1, &c1);
            float c2 = c1 * c1 - s1 * s1, s2 = 2.0f * c1 * s1;
            float c3 = c2 * c1 - s2 * s1, s3 = s2 * c1 + c2 * s1;
            float x1r = y1r * c1 - y1i * s1, x1i = y1r * s1 + y1i * c1;
            float x2r = y2r * c2 - y2i * s2, x2i = y2r * s2 + y2i * c2;
            float x3r = y3r * c3 - y3i * s3, x3i = y3r * s3 + y3i * c3;
            float B0r = y0r + x2r, B0i = y0i + x2i, B1r = y0r - x2r, B1i = y0i - x2i;
            float B2r = x1r + x3r, B2i = x1i + x3i, B3r = x1r - x3r, B3i = x1i - x3i;
            re[p0] = B0r + B2r; im[p0] = B0i + B2i;
            re[p1] = B1r - B3i; im[p1] = B1i + B3r;
            re[p2] = B0r - B2r; im[p2] = B0i - B2i;
            re[p3] = B1r + B3i; im[p3] = B1i - B3r;
        }
        __syncthreads();
    }
    const float sc = 1.0f / 4096.0f;
    for (int m = tid; m < 2048; m += 256) {
        oc[(size_t)(2 * m) * 64]     = re[PADF(m)] * sc;
        oc[(size_t)(2 * m + 1) * 64] = im[PADF(m)] * sc;
    }
}

// ---------------------------------------------------------------------------
extern "C" void kernel_launch(void* const* d_in, const int* in_sizes, int n_in,
                              void* d_out, int out_size, void* d_ws, size_t ws_size,
                              hipStream_t stream) {
    const float* x        = (const float*)d_in[0];
    const float* w_in     = (const float*)d_in[1];
    const float* b_in     = (const float*)d_in[2];
    const float* w_layers = (const float*)d_in[3];
    const float* b_layers = (const float*)d_in[4];
    const float* w_out    = (const float*)d_in[5];
    const float* b_out    = (const float*)d_in[6];
    float* out = (float*)d_out;
    float* wsf = (float*)d_ws;

    // ws layout (floats):
    //   res[4097*1024] | r[4097*64] | tw4096[8192] | tw8192[8192] | e64[128+pad]
    //   | Y[nc * 64*64*64 * 2]
    const size_t off_res    = 0;
    const size_t off_r      = 4195328;           // 4097*1024
    const size_t off_tw4096 = 4457536;           // + 4097*64  (16B aligned)
    const size_t off_tw8192 = off_tw4096 + 8192;
    const size_t off_e64    = off_tw8192 + 8192;
    const size_t off_Y      = off_e64 + 192;     // 16B aligned
    const size_t Y_PER_SLAB = 524288;            // floats (2 MB) per slab

    float* res = wsf + off_res;
    const size_t avail_f = ws_size / 4;
    int nc = 0;
    if (avail_f > off_Y)
        nc = (int)((avail_f - off_Y) / Y_PER_SLAB);
    if (nc > 64) nc = 64;

    if (nc >= 1) {
        float2* tw4096 = (float2*)(wsf + off_tw4096);
        float2* tw8192 = (float2*)(wsf + off_tw8192);
        float2* e64    = (float2*)(wsf + off_e64);
        float2* Y      = (float2*)(wsf + off_Y);
        gen_tw_kernel<<<17, 512, 0, stream>>>(tw4096, tw8192, e64);
        mlp_hidden_kernel<<<1025, 256, 0, stream>>>(w_in, b_in, w_layers, b_layers,
                                                    wsf + off_r);
        mlp_out_kernel<<<dim3(4, 257), 256, 0, stream>>>(wsf + off_r, w_out, b_out, res);
        for (int s0 = 0; s0 < 64; s0 += nc) {
            int cur = (64 - s0 < nc) ? (64 - s0) : nc;
            fwd1_kernel<<<dim3(128, cur), 256, 0, stream>>>(x, Y, tw4096, e64, s0);
            midspec_kernel<<<dim3(132, cur), 256, 0, stream>>>(Y, res, tw4096, tw8192,
                                                               e64, s0);
            inv2_kernel<<<dim3(128, cur), 256, 0, stream>>>(Y, out, e64, s0);
        }
    } else {
        rpe_mlp_kernel<<<4097, 64, 0, stream>>>(w_in, b_in, w_layers, b_layers,
                                                w_out, b_out, res);
        fftconv_kernel<<<4096, 256, 0, stream>>>(x, res, out);
    }
}

// Round 11
// 247.857 us; speedup vs baseline: 1.1367x; 1.1367x over previous
//
#include <hip/hip_runtime.h>
#include <hip/hip_fp16.h>
#include <math.h>

// B=8, H=8, N=4096, D=64 ; fft_size=8192, nf=4097 ; packed complex FFT M=4096
// Four-step: 4096 = 64 x 64.  m = 64*m1 + m0,  k = 64*k0 + k1.
// Round 11: identical resubmit of round 10 (GPU acquisition timeout — infra).
// Round-8 structure (64-col LDS tiles, conflict-free wave accesses,
// radix-8 x radix-8 in-register FFT64) + Y intermediate stored as fp16
// (__half2 per complex) -> halves 536 MB of the 670 MB traffic.

#define PI_F 3.14159265358979323846f
#define TWO_PI_F 6.283185307179586f

__device__ __forceinline__ int r8(int k) {   // swap the two base-8 digits
    return ((k & 7) << 3) | (k >> 3);
}

// ---------------------------------------------------------------------------
// Twiddle tables (global): tw4096[j]=(cos,sin)(2pi j/4096); tw8192[j] same /8192
// (j<4096); e64[j]=(cos,sin)(2pi j/64), j<64.
// ---------------------------------------------------------------------------
__global__ __launch_bounds__(512) void gen_tw_kernel(float2* __restrict__ tw4096,
                                                     float2* __restrict__ tw8192,
                                                     float2* __restrict__ e64)
{
    int idx = blockIdx.x * 512 + threadIdx.x;
    if (idx < 4096) {
        float s, c; __sincosf(TWO_PI_F * (float)idx * (1.0f / 4096.0f), &s, &c);
        tw4096[idx] = make_float2(c, s);
    } else if (idx < 8192) {
        int j = idx - 4096;
        float s, c; __sincosf(TWO_PI_F * (float)j * (1.0f / 8192.0f), &s, &c);
        tw8192[j] = make_float2(c, s);
    } else if (idx < 8256) {
        int j = idx - 8192;
        float s, c; __sincosf(TWO_PI_F * (float)j * (1.0f / 64.0f), &s, &c);
        e64[j] = make_float2(c, s);
    }
}

// ---------------------------------------------------------------------------
// 8-point FFT in registers. sgn=-1: X[k]=sum e^{-2pi i nk/8} x[n]; sgn=+1 conj.
// ---------------------------------------------------------------------------
__device__ __forceinline__ void fft8_regs(float2* v, float sgn) {
    float t0r = v[0].x + v[4].x, t0i = v[0].y + v[4].y;
    float t1r = v[0].x - v[4].x, t1i = v[0].y - v[4].y;
    float t2r = v[2].x + v[6].x, t2i = v[2].y + v[6].y;
    float t3r = v[2].x - v[6].x, t3i = v[2].y - v[6].y;
    float e0r = t0r + t2r, e0i = t0i + t2i;
    float e2r = t0r - t2r, e2i = t0i - t2i;
    float e1r = t1r - sgn * t3i, e1i = t1i + sgn * t3r;   // t1 + sgn*i*t3
    float e3r = t1r + sgn * t3i, e3i = t1i - sgn * t3r;
    float u0r = v[1].x + v[5].x, u0i = v[1].y + v[5].y;
    float u1r = v[1].x - v[5].x, u1i = v[1].y - v[5].y;
    float u2r = v[3].x + v[7].x, u2i = v[3].y + v[7].y;
    float u3r = v[3].x - v[7].x, u3i = v[3].y - v[7].y;
    float o0r = u0r + u2r, o0i = u0i + u2i;
    float o2r = u0r - u2r, o2i = u0i - u2i;
    float o1r = u1r - sgn * u3i, o1i = u1i + sgn * u3r;
    float o3r = u1r + sgn * u3i, o3i = u1i - sgn * u3r;
    const float C = 0.70710678118654752f;
    float w1r = C * (o1r - sgn * o1i), w1i = C * (o1i + sgn * o1r);
    float w2r = -sgn * o2i,            w2i = sgn * o2r;
    float w3r = -C * (o3r + sgn * o3i), w3i = C * (sgn * o3r - o3i);
    v[0] = make_float2(e0r + o0r, e0i + o0i);
    v[4] = make_float2(e0r - o0r, e0i - o0i);
    v[1] = make_float2(e1r + w1r, e1i + w1i);
    v[5] = make_float2(e1r - w1r, e1i - w1i);
    v[2] = make_float2(e2r + w2r, e2i + w2i);
    v[6] = make_float2(e2r - w2r, e2i - w2i);
    v[3] = make_float2(e3r + w3r, e3i + w3i);
    v[7] = make_float2(e3r - w3r, e3i - w3i);
}

// ---------------------------------------------------------------------------
// FFT64 over rows of zz[64][64] (float2). 256 threads: col=tid&63, j0=tid>>6,
// each thread handles j in {j0, j0+4}. Whole wave shares j -> every LDS access
// is one contiguous 512B block (conflict-free).
// DIF: natural rows in -> slot r8(k) out. DIT: slot r8(k) in -> natural out.
// ---------------------------------------------------------------------------
__device__ __forceinline__ void fft64_dif(float2* zz, int col, int j0, float sgn,
                                          bool act, const float2* e64s) {
    if (act) {
        #pragma unroll
        for (int jj = 0; jj < 2; ++jj) {
            const int j = j0 + jj * 4;
            float2 v[8];
            #pragma unroll
            for (int r = 0; r < 8; ++r) v[r] = zz[(8 * r + j) * 64 + col];
            fft8_regs(v, sgn);
            #pragma unroll
            for (int r = 1; r < 8; ++r) {
                float2 t = e64s[j * r];
                float c = t.x, s = sgn * t.y;
                float vr = v[r].x, vi = v[r].y;
                v[r] = make_float2(vr * c - vi * s, vr * s + vi * c);
            }
            #pragma unroll
            for (int r = 0; r < 8; ++r) zz[(8 * r + j) * 64 + col] = v[r];
        }
    }
    __syncthreads();
    if (act) {
        #pragma unroll
        for (int jj = 0; jj < 2; ++jj) {
            const int j = j0 + jj * 4;
            float2 v[8];
            #pragma unroll
            for (int r = 0; r < 8; ++r) v[r] = zz[(8 * j + r) * 64 + col];
            fft8_regs(v, sgn);
            #pragma unroll
            for (int r = 0; r < 8; ++r) zz[(8 * j + r) * 64 + col] = v[r];
        }
    }
    __syncthreads();
}

__device__ __forceinline__ void fft64_dit(float2* zz, int col, int j0, float sgn,
                                          bool act, const float2* e64s) {
    if (act) {
        #pragma unroll
        for (int jj = 0; jj < 2; ++jj) {
            const int j = j0 + jj * 4;
            float2 v[8];
            #pragma unroll
            for (int r = 0; r < 8; ++r) v[r] = zz[(8 * j + r) * 64 + col];
            fft8_regs(v, sgn);
            #pragma unroll
            for (int r = 1; r < 8; ++r) {
                float2 t = e64s[j * r];
                float c = t.x, s = sgn * t.y;
                float vr = v[r].x, vi = v[r].y;
                v[r] = make_float2(vr * c - vi * s, vr * s + vi * c);
            }
            #pragma unroll
            for (int r = 0; r < 8; ++r) zz[(8 * j + r) * 64 + col] = v[r];
        }
    }
    __syncthreads();
    if (act) {
        #pragma unroll
        for (int jj = 0; jj < 2; ++jj) {
            const int j = j0 + jj * 4;
            float2 v[8];
            #pragma unroll
            for (int r = 0; r < 8; ++r) v[r] = zz[(8 * r + j) * 64 + col];
            fft8_regs(v, sgn);
            #pragma unroll
            for (int r = 0; r < 8; ++r) zz[(8 * r + j) * 64 + col] = v[r];
        }
    }
    __syncthreads();
}

// ---------------------------------------------------------------------------
// MLP stage 1: hidden activations r[k][64].
// ---------------------------------------------------------------------------
__global__ __launch_bounds__(256) void mlp_hidden_kernel(
    const float* __restrict__ w_in, const float* __restrict__ b_in,
    const float* __restrict__ w_layers, const float* __restrict__ b_layers,
    float* __restrict__ rbuf)
{
    const int lane = threadIdx.x & 63;
    const int k = blockIdx.x * 4 + (threadIdx.x >> 6);
    if (k > 4096) return;
    const float pos = PI_F * (float)k * (1.0f / 4096.0f);
    float xv = fmaf(pos, w_in[lane], b_in[lane]);
    for (int l = 0; l < 3; ++l) {
        float ss = xv * xv;
        #pragma unroll
        for (int o = 1; o < 64; o <<= 1) ss += __shfl_xor(ss, o, 64);
        float r = xv / (sqrtf(ss * (1.0f / 64.0f)) + 1e-8f);
        r = fmaxf(r, 0.0f);
        const float* W = w_layers + l * 4096;
        float a0 = 0.f, a1 = 0.f, a2 = 0.f, a3 = 0.f;
        for (int i = 0; i < 64; i += 4) {
            a0 = fmaf(__shfl(r, i, 64),     W[(i) * 64 + lane],     a0);
            a1 = fmaf(__shfl(r, i + 1, 64), W[(i + 1) * 64 + lane], a1);
            a2 = fmaf(__shfl(r, i + 2, 64), W[(i + 2) * 64 + lane], a2);
            a3 = fmaf(__shfl(r, i + 3, 64), W[(i + 3) * 64 + lane], a3);
        }
        xv = ((a0 + a1) + (a2 + a3)) + b_layers[l * 64 + lane];
    }
    float ss = xv * xv;
    #pragma unroll
    for (int o = 1; o < 64; o <<= 1) ss += __shfl_xor(ss, o, 64);
    float r = xv / (sqrtf(ss * (1.0f / 64.0f)) + 1e-8f);
    r = fmaxf(r, 0.0f);
    rbuf[(size_t)k * 64 + lane] = r;
}

// ---------------------------------------------------------------------------
// MLP stage 2: res[4097][1024] = r @ w_out + b_out.
// ---------------------------------------------------------------------------
__global__ __launch_bounds__(256) void mlp_out_kernel(
    const float* __restrict__ rbuf, const float* __restrict__ w_out,
    const float* __restrict__ b_out, float* __restrict__ res)
{
    __shared__ float rl[16 * 64];
    const int tid = threadIdx.x;
    const int nt = blockIdx.x, kt = blockIdx.y;
    for (int it = 0; it < 4; ++it) {
        int idx = it * 256 + tid;
        int row = idx >> 6, i = idx & 63;
        int k = kt * 16 + row;
        rl[idx] = (k <= 4096) ? rbuf[(size_t)k * 64 + i] : 0.0f;
    }
    __syncthreads();
    const int n = nt * 256 + tid;
    float acc[16];
    #pragma unroll
    for (int j = 0; j < 16; ++j) acc[j] = 0.0f;
    for (int i = 0; i < 64; ++i) {
        float wv = w_out[(size_t)i * 1024 + n];
        #pragma unroll
        for (int j = 0; j < 16; ++j)
            acc[j] = fmaf(rl[j * 64 + i], wv, acc[j]);
    }
    float bv = b_out[n];
    for (int j = 0; j < 16; ++j) {
        int k = kt * 16 + j;
        if (k <= 4096) res[(size_t)k * 1024 + n] = acc[j] + bv;
    }
}

// ---------------------------------------------------------------------------
// Stage A: per (lslab, m0): FFT64 over m1 (upper half zero), twiddle
// W4096^{-m0*k1}, write Y[lslab][k1][m0][d] as __half2.
// ---------------------------------------------------------------------------
__global__ __launch_bounds__(256) void fwd1_kernel(const float* __restrict__ x,
                                                   __half2* __restrict__ Y,
                                                   const float2* __restrict__ tw4096,
                                                   const float2* __restrict__ e64g,
                                                   int slab_base)
{
    __shared__ float2 zz[4096];            // [m1 64][d 64]
    __shared__ float2 e64s[64];
    __shared__ float2 twA[64];             // twA[k1] = tw4096[m0*k1]
    const int tid = threadIdx.x;
    const int m0 = blockIdx.x, lslab = blockIdx.y;
    if (tid < 64) e64s[tid] = e64g[tid];
    else if (tid < 128) twA[tid - 64] = tw4096[m0 * (tid - 64)];
    const float* xs = x + (size_t)(slab_base + lslab) * 262144;
    for (int it = 0; it < 16; ++it) {
        int slot = it * 256 + tid;           // m1*64 + d
        int m1 = slot >> 6, d = slot & 63;
        if (m1 < 32) {
            float vr = xs[(size_t)(128 * m1 + 2 * m0) * 64 + d];
            float vi = xs[(size_t)(128 * m1 + 2 * m0 + 1) * 64 + d];
            zz[slot] = make_float2(vr, vi);
        } else {
            zz[slot] = make_float2(0.0f, 0.0f);
        }
    }
    __syncthreads();
    const int col = tid & 63, j0 = tid >> 6;
    fft64_dif(zz, col, j0, -1.0f, true, e64s);
    __half2* Ys = Y + (size_t)lslab * 262144 + (size_t)m0 * 64;
    for (int og = 0; og < 16; ++og) {
        int k1 = og * 4 + j0;
        float2 v = zz[r8(k1) * 64 + col];
        float2 t = twA[k1];                  // angle -2pi*m0*k1/4096
        float c = t.x, s = -t.y;
        Ys[(size_t)k1 * 4096 + col] = __floats2half2_rn(v.x * c - v.y * s,
                                                        v.x * s + v.y * c);
    }
}

// ---------------------------------------------------------------------------
// Stage B (IN-PLACE on Y, d-half split): block=(k1-pair, dh, lslab).
// FFT64 over m0 -> C at slot r8(k0); spectral on pairs (k, 4096-k); inverse
// FFT64 (DIT) -> natural m0; twiddle W4096^{+m0*k1}; write back fp16.
// LDS cols: plane A = [0,32), plane B = [32,64).
// ---------------------------------------------------------------------------
__global__ __launch_bounds__(256) void midspec_kernel(__half2* __restrict__ Y,
                                                      const float* __restrict__ res,
                                                      const float2* __restrict__ tw4096,
                                                      const float2* __restrict__ tw8192,
                                                      const float2* __restrict__ e64g,
                                                      int slab_base)
{
    __shared__ float2 zz[4096];            // [row 64][col 64]: A=[0,32) B=[32,64)
    __shared__ float2 e64s[64];
    __shared__ float2 twS[64];             // twS[k0] = tw8192[k0*64+k1a]
    __shared__ float2 twB[128];            // twB[pl*64+m0] = tw4096[m0*k1(pl)]
    const int tid = threadIdx.x;
    const int bx = blockIdx.x;             // 0..65
    const int k1p = bx >> 1, dh = bx & 1;
    const int lslab = blockIdx.y;
    const int h = (slab_base + lslab) & 7;
    const bool pairwg = (k1p >= 1 && k1p <= 31);
    const int k1a = k1p;
    const int k1b = pairwg ? (64 - k1p) : k1p;
    const int NC = pairwg ? 64 : 32;

    if (tid < 64) e64s[tid] = e64g[tid];
    else if (tid < 128) twS[tid - 64] = tw8192[(tid - 64) * 64 + k1a];
    else {
        int i = tid - 128;                 // 0..127
        int kk1 = (i < 64) ? k1a : k1b;
        twB[i] = tw4096[(i & 63) * kk1];
    }

    // load plane rows as float4 = 4 complex (half2); 128B per row-half
    const float4* Pa4 = (const float4*)(Y + (size_t)lslab * 262144 + (size_t)k1a * 4096);
    for (int it = 0; it < 2; ++it) {
        int idx = it * 256 + tid;          // 0..511 : m0*8 + f
        int m0 = idx >> 3, f = idx & 7;
        float4 v = Pa4[m0 * 16 + 8 * dh + f];
        const __half2* hv = (const __half2*)&v;
        #pragma unroll
        for (int i = 0; i < 4; ++i)
            zz[m0 * 64 + 4 * f + i] = __half22float2(hv[i]);
    }
    if (pairwg) {
        const float4* Pb4 = (const float4*)(Y + (size_t)lslab * 262144 + (size_t)k1b * 4096);
        for (int it = 0; it < 2; ++it) {
            int idx = it * 256 + tid;
            int m0 = idx >> 3, f = idx & 7;
            float4 v = Pb4[m0 * 16 + 8 * dh + f];
            const __half2* hv = (const __half2*)&v;
            #pragma unroll
            for (int i = 0; i < 4; ++i)
                zz[m0 * 64 + 32 + 4 * f + i] = __half22float2(hv[i]);
        }
    }
    __syncthreads();
    const int col = tid & 63, j0 = tid >> 6;
    fft64_dif(zz, col, j0, -1.0f, col < NC, e64s);

    // spectral multiply on conjugate pairs; each slot touched exactly once
    const int nit = pairwg ? 8 : 4;
    for (int it = 0; it < nit; ++it) {
        int item = it * 256 + tid;         // k0*32 + dl
        int k0 = item >> 5, dl = item & 31;
        int c = h * 128 + 32 * dh + dl;
        if (k1p == 0 && k0 == 0) {
            // DC (k=0, slot row r8(0)=0) and k=2048 (k0=32, slot row r8(32)=4)
            float2 C0 = zz[dl];
            float X0 = C0.x + C0.y, XN = C0.x - C0.y;
            float a0 = res[c], aN = res[(size_t)4096 * 1024 + c];
            float S0 = a0 * X0, SN = aN * XN;
            zz[dl] = make_float2(0.5f * (S0 + SN), 0.5f * (S0 - SN));
            int p2 = 4 * 64 + dl;
            float2 Cq = zz[p2];
            float ar = res[(size_t)2048 * 1024 + c], ai = res[(size_t)2048 * 1024 + c + 64];
            float Sr = ar * Cq.x + ai * Cq.y;
            float Si = ai * Cq.x - ar * Cq.y;
            zz[p2] = make_float2(Sr, -Si);
        } else {
            int k0p, coff;
            if (pairwg)          { k0p = 63 - k0;        coff = 32; }
            else if (k1p == 0)   { k0p = (64 - k0) & 63; coff = 0;  }
            else /* k1p == 32 */ { k0p = 63 - k0;        coff = 0;  }
            int sa = r8(k0)  * 64 + dl;
            int sb = r8(k0p) * 64 + coff + dl;
            int k  = k0 * 64 + k1a;
            int km = 4096 - k;
            float2 Ck = zz[sa], Cm = zz[sb];
            float Er = 0.5f * (Ck.x + Cm.x), Ei = 0.5f * (Ck.y - Cm.y);
            float Dr = 0.5f * (Ck.x - Cm.x), Di = 0.5f * (Ck.y + Cm.y);
            float Or = Di, Oi = -Dr;
            float2 tk = twS[k0];                 // angle -2pi*k/8192 -> conj
            float cw = tk.x, sw = -tk.y;
            float Tr = Or * cw - Oi * sw, Ti = Or * sw + Oi * cw;
            float Xkr = Er + Tr, Xki = Ei + Ti;
            float Xmr = Er - Tr, Xmi = Ti - Ei;
            float akr = res[(size_t)k * 1024 + c],  aki = res[(size_t)k * 1024 + c + 64];
            float amr = res[(size_t)km * 1024 + c], ami = res[(size_t)km * 1024 + c + 64];
            float Skr = akr * Xkr - aki * Xki, Ski = akr * Xki + aki * Xkr;
            float Smr = amr * Xmr - ami * Xmi, Smi = amr * Xmi + ami * Xmr;
            float Epr = 0.5f * (Skr + Smr), Epi = 0.5f * (Ski - Smi);
            float Ddr = 0.5f * (Skr - Smr), Ddi = 0.5f * (Ski + Smi);
            float Opr = Ddr * cw + Ddi * sw, Opi = Ddi * cw - Ddr * sw;
            zz[sa] = make_float2(Epr - Opi, Epi + Opr);
            zz[sb] = make_float2(Epr + Opi, Opr - Epi);
        }
    }
    __syncthreads();
    fft64_dit(zz, col, j0, +1.0f, col < NC, e64s);

    // write back IN-PLACE (fp16) to the same Y plane halves this block loaded
    const int nit2 = pairwg ? 16 : 8;
    for (int it = 0; it < nit2; ++it) {
        int item = it * 256 + tid;          // pl*2048 + m0*32 + dl
        int pl = item >> 11, rem = item & 2047;
        int m0 = rem >> 5, dl = rem & 31;
        int k1 = pl ? k1b : k1a;
        float2 v = zz[m0 * 64 + pl * 32 + dl];
        float2 t = twB[pl * 64 + m0];       // angle +2pi*m0*k1/4096
        float c2 = t.x, s = t.y;
        Y[(size_t)lslab * 262144 + (size_t)k1 * 4096 + (size_t)m0 * 64 + 32 * dh + dl] =
            __floats2half2_rn(v.x * c2 - v.y * s, v.x * s + v.y * c2);
    }
}

// ---------------------------------------------------------------------------
// Stage C: per (lslab, m0): inverse FFT64 over k1 (natural in -> r8 out);
// z'[64m1+m0] at slot r8(m1); write out rows 2m, 2m+1 for m1<32.
// ---------------------------------------------------------------------------
__global__ __launch_bounds__(256) void inv2_kernel(const __half2* __restrict__ Y,
                                                   float* __restrict__ out,
                                                   const float2* __restrict__ e64g,
                                                   int slab_base)
{
    __shared__ float2 zz[4096];            // [k1 64][d 64]
    __shared__ float2 e64s[64];
    const int tid = threadIdx.x;
    const int m0 = blockIdx.x, lslab = blockIdx.y;
    if (tid < 64) e64s[tid] = e64g[tid];
    const float4* Ys4 = (const float4*)(Y + (size_t)lslab * 262144 + (size_t)m0 * 64);
    for (int it = 0; it < 4; ++it) {
        int idx = it * 256 + tid;           // 0..1023 : k1*16 + f
        int k1 = idx >> 4, f = idx & 15;
        float4 v = Ys4[k1 * 1024 + f];      // row k1 = 4096 half2 = 1024 float4
        const __half2* hv = (const __half2*)&v;
        #pragma unroll
        for (int i = 0; i < 4; ++i)
            zz[k1 * 64 + 4 * f + i] = __half22float2(hv[i]);
    }
    __syncthreads();
    const int col = tid & 63, j0 = tid >> 6;
    fft64_dif(zz, col, j0, +1.0f, true, e64s);
    float* os = out + (size_t)(slab_base + lslab) * 262144;
    const float sc = 1.0f / 4096.0f;
    for (int it = 0; it < 8; ++it) {
        int slot = it * 256 + tid;          // m1*64 + d, m1 < 32
        int m1 = slot >> 6, d = slot & 63;
        float2 v = zz[r8(m1) * 64 + d];
        os[(size_t)(128 * m1 + 2 * m0) * 64 + d]     = v.x * sc;
        os[(size_t)(128 * m1 + 2 * m0 + 1) * 64 + d] = v.y * sc;
    }
}

// ===========================================================================
// Fallback path (round-1, verified): monolithic per-column kernel
// ===========================================================================
#define PADF(i) ((i) + ((i) >> 5))

__device__ __forceinline__ unsigned dr4_12(unsigned k) {
    unsigned rb = __brev(k) >> 20;
    return ((rb & 0x555u) << 1) | ((rb >> 1) & 0x555u);
}

__global__ __launch_bounds__(64) void rpe_mlp_kernel(
    const float* __restrict__ w_in, const float* __restrict__ b_in,
    const float* __restrict__ w_layers, const float* __restrict__ b_layers,
    const float* __restrict__ w_out, const float* __restrict__ b_out,
    float* __restrict__ res)
{
    const int k = blockIdx.x;
    const int lane = threadIdx.x;
    const float pos = PI_F * (float)k * (1.0f / 4096.0f);
    float xv = fmaf(pos, w_in[lane], b_in[lane]);
    for (int l = 0; l < 3; ++l) {
        float ss = xv * xv;
        #pragma unroll
        for (int o = 1; o < 64; o <<= 1) ss += __shfl_xor(ss, o, 64);
        float rms = sqrtf(ss * (1.0f / 64.0f));
        float r = xv / (rms + 1e-8f);
        r = r > 0.0f ? r : 0.0f;
        const float* W = w_layers + l * 64 * 64;
        float acc = b_layers[l * 64 + lane];
        for (int i = 0; i < 64; ++i)
            acc = fmaf(__shfl(r, i, 64), W[i * 64 + lane], acc);
        xv = acc;
    }
    float ss = xv * xv;
    #pragma unroll
    for (int o = 1; o < 64; o <<= 1) ss += __shfl_xor(ss, o, 64);
    float rms = sqrtf(ss * (1.0f / 64.0f));
    float r = xv / (rms + 1e-8f);
    r = r > 0.0f ? r : 0.0f;
    float acc[16];
    #pragma unroll
    for (int u = 0; u < 16; ++u) acc[u] = b_out[u * 64 + lane];
    for (int i = 0; i < 64; ++i) {
        float rv = __shfl(r, i, 64);
        const float* Wrow = w_out + i * 1024;
        #pragma unroll
        for (int u = 0; u < 16; ++u)
            acc[u] = fmaf(rv, Wrow[u * 64 + lane], acc[u]);
    }
    float* dst = res + (size_t)k * 1024;
    #pragma unroll
    for (int u = 0; u < 16; ++u) dst[u * 64 + lane] = acc[u];
}

__global__ __launch_bounds__(256) void fftconv_kernel(
    const float* __restrict__ x, const float* __restrict__ res,
    float* __restrict__ out)
{
    __shared__ float re[PADF(4095) + 1];
    __shared__ float im[PADF(4095) + 1];
    const int tid = threadIdx.x;
    const int blk = blockIdx.x;
    const int d = (blk >> 3) & 63;
    const int slab = (blk & 7) | ((blk >> 9) << 3);
    const int h = slab & 7;
    const size_t base = (size_t)slab * 4096 * 64 + (size_t)d;
    const float* xc = x + base;
    float* oc = out + base;
    const int c = h * 128 + d;
    for (int m = tid; m < 2048; m += 256) {
        re[PADF(m)] = xc[(size_t)(2 * m) * 64];
        im[PADF(m)] = xc[(size_t)(2 * m + 1) * 64];
    }
    for (int m = 2048 + tid; m < 4096; m += 256) { re[PADF(m)] = 0.0f; im[PADF(m)] = 0.0f; }
    __syncthreads();
    for (int S = 1024; S >= 1; S >>= 2) {
        const float ab = -TWO_PI_F / (float)(4 * S);
        for (int j = tid; j < 1024; j += 256) {
            const int q = j & (S - 1);
            const int i0 = ((j & ~(S - 1)) << 2) | q;
            const int p0 = PADF(i0), p1 = PADF(i0 + S), p2 = PADF(i0 + 2 * S), p3 = PADF(i0 + 3 * S);
            float x0r = re[p0], x0i = im[p0], x1r = re[p1], x1i = im[p1];
            float x2r = re[p2], x2i = im[p2], x3r = re[p3], x3i = im[p3];
            float A0r = x0r + x2r, A0i = x0i + x2i, A1r = x0r - x2r, A1i = x0i - x2i;
            float A2r = x1r + x3r, A2i = x1i + x3i, A3r = x1r - x3r, A3i = x1i - x3i;
            float s1, c1; __sincosf(ab * (float)q, &s1, &c1);
            float c2 = c1 * c1 - s1 * s1, s2 = 2.0f * c1 * s1;
            float c3 = c2 * c1 - s2 * s1, s3 = s2 * c1 + c2 * s1;
            re[p0] = A0r + A2r; im[p0] = A0i + A2i;
            float t1r = A1r + A3i, t1i = A1i - A3r;
            re[p1] = t1r * c1 - t1i * s1; im[p1] = t1r * s1 + t1i * c1;
            float t2r = A0r - A2r, t2i = A0i - A2i;
            re[p2] = t2r * c2 - t2i * s2; im[p2] = t2r * s2 + t2i * c2;
            float t3r = A1r - A3i, t3i = A1i + A3r;
            re[p3] = t3r * c3 - t3i * s3; im[p3] = t3r * s3 + t3i * c3;
        }
        __syncthreads();
    }
    for (int k = tid; k <= 2048; k += 256) {
        if (k == 0) {
            float C0r = re[0], C0i = im[0];
            float X0 = C0r + C0i, XN = C0r - C0i;
            float a0 = res[c], aN = res[(size_t)4096 * 1024 + c];
            float S0 = a0 * X0, SN = aN * XN;
            re[0] = 0.5f * (S0 + SN); im[0] = 0.5f * (S0 - SN);
        } else if (k == 2048) {
            const int p = PADF(2);
            float Cr = re[p], Ci = im[p];
            float ar = res[(size_t)2048 * 1024 + c], ai = res[(size_t)2048 * 1024 + c + 64];
            float Sr = ar * Cr + ai * Ci, Si = ai * Cr - ar * Ci;
            re[p] = Sr; im[p] = -Si;
        } else {
            const int pk = PADF((int)dr4_12((unsigned)k));
            const int pm = PADF((int)dr4_12((unsigned)(4096 - k)));
            float Ckr = re[pk], Cki = im[pk];
            float Cmr = re[pm], Cmi = im[pm];
            float Er = 0.5f * (Ckr + Cmr), Ei = 0.5f * (Cki - Cmi);
            float Dr = 0.5f * (Ckr - Cmr), Di = 0.5f * (Cki + Cmi);
            float Or = Di, Oi = -Dr;
            float sw, cw; __sincosf(-TWO_PI_F * (float)k * (1.0f / 8192.0f), &sw, &cw);
            float Tr = Or * cw - Oi * sw, Ti = Or * sw + Oi * cw;
            float Xkr = Er + Tr, Xki = Ei + Ti;
            float Xmr = Er - Tr, Xmi = Ti - Ei;
            float akr = res[(size_t)k * 1024 + c], aki = res[(size_t)k * 1024 + c + 64];
            float amr = res[(size_t)(4096 - k) * 1024 + c], ami = res[(size_t)(4096 - k) * 1024 + c + 64];
            float Skr = akr * Xkr - aki * Xki, Ski = akr * Xki + aki * Xkr;
            float Smr = amr * Xmr - ami * Xmi, Smi = amr * Xmi + ami * Xmr;
            float Epr = 0.5f * (Skr + Smr), Epi = 0.5f * (Ski - Smi);
            float Ddr = 0.5f * (Skr - Smr), Ddi = 0.5f * (Ski + Smi);
            float Opr = Ddr * cw + Ddi * sw, Opi = Ddi * cw - Ddr * sw;
            re[pk] = Epr - Opi; im[pk] = Epi + Opr;
            re[pm] = Epr + Opi; im[pm] = Opr - Epi;
        }
    }
    __syncthreads();
    for (int S = 1; S <= 1024; S <<= 2) {
        const float ab = TWO_PI_F / (float)(4 * S);
        for (int j = tid; j < 1024; j += 256) {
            const int q = j & (S - 1);
            const int i0 = ((j & ~(S - 1)) << 2) | q;
            const int p0 = PADF(i0), p1 = PADF(i0 + S), p2 = PADF(i0 + 2 * S), p3 = PADF(i0 + 3 * S);
            float y0r = re[p0], y0i = im[p0], y1r = re[p1], y1i = im[p1];
            float y2r = re[p2], y2i = im[p2], y3r = re[p3], y3i = im[p3];
            float s1, c1; __sincosf(ab * (float)q, &s1, &c1);
            float c2 = c1 * c1 - s1 * s1, s2 = 2.0f * c1 * s1;
            float c3 = c2 * c1 - s2 * s1, s3 = s2 * c1 + c2 * s1;
            float x1r = y1r * c1 - y1i * s1, x1i = y1r * s1 + y1i * c1;
            float x2r = y2r * c2 - y2i * s2, x2i = y2r * s2 + y2i * c2;
            float x3r = y3r * c3 - y3i * s3, x3i = y3r * s3 + y3i * c3;
            float B0r = y0r + x2r, B0i = y0i + x2i, B1r = y0r - x2r, B1i = y0i - x2i;
            float B2r = x1r + x3r, B2i = x1i + x3i, B3r = x1r - x3r, B3i = x1i - x3i;
            re[p0] = B0r + B2r; im[p0] = B0i + B2i;
            re[p1] = B1r - B3i; im[p1] = B1i + B3r;
            re[p2] = B0r - B2r; im[p2] = B0i - B2i;
            re[p3] = B1r + B3i; im[p3] = B1i - B3r;
        }
        __syncthreads();
    }
    const float sc = 1.0f / 4096.0f;
    for (int m = tid; m < 2048; m += 256) {
        oc[(size_t)(2 * m) * 64]     = re[PADF(m)] * sc;
        oc[(size_t)(2 * m + 1) * 64] = im[PADF(m)] * sc;
    }
}

// ---------------------------------------------------------------------------
extern "C" void kernel_launch(void* const* d_in, const int* in_sizes, int n_in,
                              void* d_out, int out_size, void* d_ws, size_t ws_size,
                              hipStream_t stream) {
    const float* x        = (const float*)d_in[0];
    const float* w_in     = (const float*)d_in[1];
    const float* b_in     = (const float*)d_in[2];
    const float* w_layers = (const float*)d_in[3];
    const float* b_layers = (const float*)d_in[4];
    const float* w_out    = (const float*)d_in[5];
    const float* b_out    = (const float*)d_in[6];
    float* out = (float*)d_out;
    float* wsf = (float*)d_ws;

    // ws layout (floats):
    //   res[4097*1024] | r[4097*64] | tw4096[8192] | tw8192[8192] | e64[128+pad]
    //   | Y[nc * 64*64*64] (half2 = 1 float per complex)
    const size_t off_res    = 0;
    const size_t off_r      = 4195328;           // 4097*1024
    const size_t off_tw4096 = 4457536;           // + 4097*64  (16B aligned)
    const size_t off_tw8192 = off_tw4096 + 8192;
    const size_t off_e64    = off_tw8192 + 8192;
    const size_t off_Y      = off_e64 + 192;     // 16B aligned
    const size_t Y_PER_SLAB = 262144;            // floats (1 MB) per slab, fp16

    float* res = wsf + off_res;
    const size_t avail_f = ws_size / 4;
    int nc = 0;
    if (avail_f > off_Y)
        nc = (int)((avail_f - off_Y) / Y_PER_SLAB);
    if (nc > 64) nc = 64;

    if (nc >= 1) {
        float2* tw4096 = (float2*)(wsf + off_tw4096);
        float2* tw8192 = (float2*)(wsf + off_tw8192);
        float2* e64    = (float2*)(wsf + off_e64);
        __half2* Y     = (__half2*)(wsf + off_Y);
        gen_tw_kernel<<<17, 512, 0, stream>>>(tw4096, tw8192, e64);
        mlp_hidden_kernel<<<1025, 256, 0, stream>>>(w_in, b_in, w_layers, b_layers,
                                                    wsf + off_r);
        mlp_out_kernel<<<dim3(4, 257), 256, 0, stream>>>(wsf + off_r, w_out, b_out, res);
        for (int s0 = 0; s0 < 64; s0 += nc) {
            int cur = (64 - s0 < nc) ? (64 - s0) : nc;
            fwd1_kernel<<<dim3(64, cur), 256, 0, stream>>>(x, Y, tw4096, e64, s0);
            midspec_kernel<<<dim3(66, cur), 256, 0, stream>>>(Y, res, tw4096, tw8192,
                                                              e64, s0);
            inv2_kernel<<<dim3(64, cur), 256, 0, stream>>>(Y, out, e64, s0);
        }
    } else {
        rpe_mlp_kernel<<<4097, 64, 0, stream>>>(w_in, b_in, w_layers, b_layers,
                                                w_out, b_out, res);
        fftconv_kernel<<<4096, 256, 0, stream>>>(x, res, out);
    }
}